// Round 2
// baseline (220.654 us; speedup 1.0000x reference)
//
#include <hip/hip_runtime.h>

// VQ-VAE quantization. x: [32,64,64,64] fp32, emb: [1024,64] fp32
#define BATCH   32
#define CCH     64
#define HW      4096
#define NPIX    (BATCH * HW)        // 131072
#define KCODES  1024
#define NELEM   (NPIX * CCH)        // 8388608
#define MB      128                 // pixels per block (16 per wave, 8 waves) -> 1024 blocks, 4/CU
#define CK      64                  // codes per LDS chunk (16 chunks)
#define MARGIN_Q 3u                 // ambiguity margin, 1/2048 distance units

typedef _Float16 f16;
typedef __attribute__((ext_vector_type(8))) _Float16 f16x8;
typedef __attribute__((ext_vector_type(4))) float    f32x4;

static __device__ __forceinline__ f32x4 mfma16(f16x8 a, f16x8 b, f32x4 c) {
    return __builtin_amdgcn_mfma_f32_16x16x32_f16(a, b, c, 0, 0, 0);
}

static __device__ __forceinline__ void dma16(void* lds, const void* g) {
    __builtin_amdgcn_global_load_lds(
        (const __attribute__((address_space(1))) unsigned int*)g,
        (__attribute__((address_space(3))) unsigned int*)lds, 16, 0, 0);
}

// best2' = median(best, best2, pk)  given invariant best <= best2.
static __device__ __forceinline__ unsigned med3u(unsigned a, unsigned b, unsigned c) {
    unsigned d;
    asm("v_med3_u32 %0, %1, %2, %3" : "=v"(d) : "v"(a), "v"(b), "v"(c));
    return d;
}

// ws layout (bytes):
//   [0] f32 loss acc   [4] u32 worklist count
//   [256..4352)       eeb[k] = 2048*||e_k||^2 + 2^20  (1024 f32)
//   [8192..139264)    cbH swizzled fp16-hi codebook (row r granule g at r*64 + 8*(g^(r&7)))
//   [139264..270336)  cbL fp16-lo, same swizzle
//   [270336..)        worklist (u32)
#define WS_EEB_F   64
#define WS_CBH_B   8192
#define WS_CBL_B   139264
#define WS_WL_U    67584

__global__ __launch_bounds__(256) void vq_prep(
    const float* __restrict__ emb, float* __restrict__ wsf,
    unsigned* __restrict__ wsu, f16* __restrict__ cbH, f16* __restrict__ cbL,
    float* __restrict__ eeb_g)
{
    const int t   = threadIdx.x;
    const int gid = blockIdx.x * 256 + t;        // 0..8191 granules
    const int row = gid >> 3, gi = gid & 7;
    if (gid == 0) { wsf[0] = 0.f; wsu[1] = 0u; }
    const float* src = emb + (size_t)row * CCH + gi * 8;
    float4 v0 = *(const float4*)(src);
    float4 v1 = *(const float4*)(src + 4);
    float vv[8] = {v0.x, v0.y, v0.z, v0.w, v1.x, v1.y, v1.z, v1.w};
    f16x8 h, l;
    float s = 0.f;
#pragma unroll
    for (int j = 0; j < 8; ++j) {
        f16 hh = (f16)vv[j];
        h[j] = hh;
        l[j] = (f16)(vv[j] - (float)hh);
        s = fmaf(vv[j], vv[j], s);
    }
    const int off = row * 64 + 8 * (gi ^ (row & 7));
    *(f16x8*)(cbH + off) = h;
    *(f16x8*)(cbL + off) = l;
    // ||e||^2: reduce across the 8 granule-threads of this row (adjacent lanes)
    s += __shfl_xor(s, 1, 64);
    s += __shfl_xor(s, 2, 64);
    s += __shfl_xor(s, 4, 64);
    if (gi == 0) eeb_g[row] = fmaf(s, 2048.0f, 1048576.0f);
}

// 8 waves x 16 pixels; VGPR <= 64 so 8 waves/SIMD -> 4 blocks/CU (LDS 4x34.4K = 137K <= 160K)
__global__ __launch_bounds__(512, 8) void vq_main(
    const float* __restrict__ x,
    const float* __restrict__ emb,
    const f16* __restrict__ cbH, const f16* __restrict__ cbL,
    const float* __restrict__ eeb_g,
    float* __restrict__ o, float* __restrict__ idx_out,
    float* __restrict__ acc, unsigned* __restrict__ wl_count,
    unsigned* __restrict__ wl, unsigned cap)
{
    __shared__ __align__(16) char smem[32768];      // 2 x (8K H | 8K L)
    __shared__ float eebl[2][CK];
    __shared__ unsigned bu1[MB], bu2[MB];
    __shared__ float wred[8];

    const int t    = threadIdx.x;
    const int lane = t & 63;
    const int w    = t >> 6;               // 0..7
    const int col  = lane & 15;
    const int quad = lane >> 4;
    const int c7   = col & 7;
    const int sw0  = 8 * (quad ^ c7);      // swizzled granule offset, chans 0..31
    const int sw1  = sw0 ^ 32;             // chans 32..63
    const int n0   = blockIdx.x * MB;
    const int b    = n0 >> 12;
    const int p0   = n0 & 4095;
    const float* xb = x + (size_t)b * (CCH * HW) + p0;

    // wave w stages its 1KB slice of each 8KB H/L region
    auto stage = [&](int chunk, int bufi) {
        const int k0 = chunk * CK;
        char* lb = smem + bufi * 16384;
        const char* gH = (const char*)cbH + (size_t)k0 * 128 + w * 1024 + lane * 16;
        const char* gL = (const char*)cbL + (size_t)k0 * 128 + w * 1024 + lane * 16;
        dma16(lb + w * 1024,        gH);
        dma16(lb + 8192 + w * 1024, gL);
        if (t < CK) eebl[bufi][t] = eeb_g[k0 + t];
    };

    stage(0, 0);    // DMA in flight while we build A fragments

    // ---- A fragments straight from global (MFMA A-layout, no LDS trip) ----
    // lane holds pixel (w*16 + col), chans kc*32 + quad*8 + j
    f16x8 aH[2], aL[2];
    {
        const int pp = w * 16 + col;
#pragma unroll
        for (int kc = 0; kc < 2; ++kc) {
            f16x8 h, l;
#pragma unroll
            for (int j = 0; j < 8; ++j) {
                const int c = kc * 32 + quad * 8 + j;
                float zs = -2.0f * xb[(size_t)c * HW + pp];
                f16 hh = (f16)zs;
                h[j] = hh;
                l[j] = (f16)(zs - (float)hh);
            }
            aH[kc] = h;
            aL[kc] = l;
        }
    }

    unsigned best[4], best2[4];
#pragma unroll
    for (int s = 0; s < 4; ++s) { best[s] = 0xFFFFFFFFu; best2[s] = 0xFFFFFFFFu; }

    const f32x4 zero4 = {0.f, 0.f, 0.f, 0.f};   // persistent C-init quad

    for (int chunk = 0; chunk < KCODES / CK; ++chunk) {
        const int cur = chunk & 1;
        __syncthreads();                        // chunk's DMA visible to all
        if (chunk + 1 < KCODES / CK) stage(chunk + 1, cur ^ 1);

        const f16* bufH = (const f16*)(smem + cur * 16384);
        const f16* bufL = bufH + 4096;
        const int k0 = chunk * CK;

#pragma unroll
        for (int tile = 0; tile < CK / 16; ++tile) {
            const f16* bh = bufH + (tile * 16 + col) * 64;
            const f16* bl = bufL + (tile * 16 + col) * 64;
            f16x8 bH0 = *(const f16x8*)(bh + sw0);
            f16x8 bH1 = *(const f16x8*)(bh + sw1);
            f16x8 bL0 = *(const f16x8*)(bl + sw0);
            f16x8 bL1 = *(const f16x8*)(bl + sw1);
            const float eebc = eebl[cur][tile * 16 + col];
            const unsigned kb = (unsigned)(k0 + tile * 16 + col);
            f32x4 a4 = mfma16(aH[0], bH0, zero4);
            a4 = mfma16(aH[1], bH1, a4);
            a4 = mfma16(aL[0], bH0, a4);
            a4 = mfma16(aL[1], bH1, a4);
            a4 = mfma16(aH[0], bL0, a4);
            a4 = mfma16(aH[1], bL1, a4);
#pragma unroll
            for (int r = 0; r < 4; ++r) {
                float uf = fmaf(a4[r], 2048.0f, eebc);   // in (0, 2^22)
                unsigned pk = (((unsigned)uf) << 10) | kb;
                const unsigned b0 = best[r];
                best2[r] = med3u(b0, best2[r], pk);      // single VOP3 2nd-best insert
                best[r]  = min(b0, pk);
            }
        }
    }

    // ---- cross-lane argmin reduce over the 16 code-columns ----
#pragma unroll
    for (int d = 1; d < 16; d <<= 1) {
#pragma unroll
        for (int s = 0; s < 4; ++s) {
            unsigned ob  = __shfl_xor(best[s],  d, 64);
            unsigned ob2 = __shfl_xor(best2[s], d, 64);
            best2[s] = min(min(best2[s], ob2), max(best[s], ob));
            best[s]  = min(best[s], ob);
        }
    }
    if (col == 0) {
#pragma unroll
        for (int r = 0; r < 4; ++r) {
            const int pl = w * 16 + quad * 4 + r;   // C/D row map
            bu1[pl] = best[r];
            bu2[pl] = best2[r];
        }
    }
    __syncthreads();

    // ---- epilogue: 512 threads over 128 pixels x 64 chans (16 each) ----
    const int pix = t & 127;
    const int qh  = t >> 7;                // chan group: qh*16 .. qh*16+15
    const unsigned bu = bu1[pix];
    const unsigned bidx = bu & 1023u;
    if (qh == 0) {
        idx_out[n0 + pix] = (float)bidx;
        const unsigned qg = (bu2[pix] >> 10) - (bu >> 10);
        if (qg < MARGIN_Q) {
            unsigned pos = atomicAdd(wl_count, 1u);
            if (pos < cap) wl[pos] = (unsigned)(n0 + pix);
        }
    }
    float ss = 0.f;
    {
        const float4* er4 = (const float4*)(emb + (size_t)bidx * CCH) + qh * 4;
        const float* xbt = xb + pix;
        float* ob = o + (size_t)b * (CCH * HW) + p0 + pix;
#pragma unroll
        for (int i = 0; i < 4; ++i) {
            float4 ev = er4[i];
            float evv[4] = {ev.x, ev.y, ev.z, ev.w};
#pragma unroll
            for (int q = 0; q < 4; ++q) {
                const int c = qh * 16 + i * 4 + q;
                float xv = xbt[(size_t)c * HW];
                float e  = evv[q];
                ob[(size_t)c * HW] = xv + (e - xv);
                float d = xv - e;
                ss = fmaf(d, d, ss);
            }
        }
    }
    for (int off = 32; off; off >>= 1) ss += __shfl_down(ss, off, 64);
    if (lane == 0) wred[w] = ss;
    __syncthreads();
    if (t == 0) {
        float s2 = 0.f;
#pragma unroll
        for (int q = 0; q < 8; ++q) s2 += wred[q];
        atomicAdd(acc, s2);
    }
}

// Exact fp64 refine: one BLOCK per ambiguous pixel, 4 codes per thread.
__global__ __launch_bounds__(256) void vq_refine(
    const float* __restrict__ x, const float* __restrict__ emb,
    float* __restrict__ o, float* __restrict__ idx_out,
    float* __restrict__ acc, const unsigned* __restrict__ wl_count,
    const unsigned* __restrict__ wl, unsigned cap)
{
    __shared__ float zsh[CCH];
    __shared__ double rbd[4];
    __shared__ int rbi[4];
    __shared__ int s_pk;
    unsigned cnt = *wl_count; if (cnt > cap) cnt = cap;
    const int t = threadIdx.x;

    for (unsigned i = blockIdx.x; i < cnt; i += gridDim.x) {
        const int n = (int)wl[i];
        const int b = n >> 12, p = n & 4095;
        if (t < CCH) zsh[t] = x[(size_t)b * (CCH * HW) + (size_t)t * HW + p];
        __syncthreads();

        double bd = 1e300; int bi = KCODES;
        for (int j = 0; j < 4; ++j) {
            const int k = t + j * 256;
            const float* er = emb + (size_t)k * CCH;
            double d = 0.0;
#pragma unroll
            for (int c = 0; c < CCH; ++c) {
                double tt = (double)zsh[c] - (double)er[c];
                d = fma(tt, tt, d);
            }
            if (d < bd) { bd = d; bi = k; }
        }
        for (int dlt = 1; dlt < 64; dlt <<= 1) {
            double od = __shfl_xor(bd, dlt, 64);
            int    oi = __shfl_xor(bi, dlt, 64);
            if (od < bd || (od == bd && oi < bi)) { bd = od; bi = oi; }
        }
        const int wv = t >> 6;
        if ((t & 63) == 0) { rbd[wv] = bd; rbi[wv] = bi; }
        __syncthreads();
        if (t == 0) {
            double fb = rbd[0]; int fi = rbi[0];
            for (int q = 1; q < 4; ++q)
                if (rbd[q] < fb || (rbd[q] == fb && rbi[q] < fi)) { fb = rbd[q]; fi = rbi[q]; }
            const int old = (int)idx_out[n];
            if (fi != old) { idx_out[n] = (float)fi; s_pk = (old << 16) | fi; }
            else s_pk = -1;
        }
        __syncthreads();
        const int pk = s_pk;
        if (pk >= 0 && t < CCH) {
            const int old = pk >> 16, fi = pk & 0xFFFF;
            const float xv = zsh[t];
            const float eo = emb[(size_t)old * CCH + t];
            const float en = emb[(size_t)fi  * CCH + t];
            o[(size_t)b * (CCH * HW) + (size_t)t * HW + p] = xv + (en - xv);
            const float dn = xv - en, dd = xv - eo;
            float delta = dn * dn - dd * dd;
            for (int off = 32; off; off >>= 1) delta += __shfl_down(delta, off, 64);
            if (t == 0) atomicAdd(acc, delta);
        }
        __syncthreads();
    }
}

__global__ void vq_fin(const float* __restrict__ acc, float* __restrict__ loss) {
    *loss = 1.25f * (*acc) * (1.0f / (float)NELEM);
}

extern "C" void kernel_launch(void* const* d_in, const int* in_sizes, int n_in,
                              void* d_out, int out_size, void* d_ws, size_t ws_size,
                              hipStream_t stream) {
    const float* x   = (const float*)d_in[0];
    const float* emb = (const float*)d_in[1];
    float*    out = (float*)d_out;
    float*    wsf = (float*)d_ws;
    unsigned* wsu = (unsigned*)d_ws;
    char*     wsb = (char*)d_ws;

    float* o_out    = out;
    float* loss_out = out + NELEM;
    float* idx_out  = out + NELEM + 1;
    float* eeb_g    = wsf + WS_EEB_F;
    f16*   cbH      = (f16*)(wsb + WS_CBH_B);
    f16*   cbL      = (f16*)(wsb + WS_CBL_B);
    unsigned* wl    = wsu + WS_WL_U;
    unsigned cap = 0;
    if (ws_size / 4 > WS_WL_U) {
        size_t c = ws_size / 4 - WS_WL_U;
        cap = (unsigned)(c > NPIX ? NPIX : c);
    }

    vq_prep<<<32, 256, 0, stream>>>(emb, wsf, wsu, cbH, cbL, eeb_g);
    vq_main<<<NPIX / MB, 512, 0, stream>>>(x, emb, cbH, cbL, eeb_g, o_out,
                                           idx_out, wsf, wsu + 1, wl, cap);
    vq_refine<<<512, 256, 0, stream>>>(x, emb, o_out, idx_out, wsf,
                                       wsu + 1, wl, cap);
    vq_fin<<<1, 1, 0, stream>>>(wsf, loss_out);
}

// Round 3
// 153.736 us; speedup vs baseline: 1.4353x; 1.4353x over previous
//
#include <hip/hip_runtime.h>

// VQ-VAE quantization. x: [32,64,64,64] fp32, emb: [1024,64] fp32
#define BATCH   32
#define CCH     64
#define HW      4096
#define NPIX    (BATCH * HW)        // 131072
#define KCODES  1024
#define NELEM   (NPIX * CCH)        // 8388608
#define MB      256                 // pixels per block (32 per wave, 2 row-tiles, 8 waves)
#define CK      128                 // codes per LDS chunk (8 chunks, 2x32KB dbuf -> 2 blocks/CU)
#define MARGIN_Q 3u                 // ambiguity margin, 1/2048 distance units

typedef _Float16 f16;
typedef __attribute__((ext_vector_type(8))) _Float16 f16x8;
typedef __attribute__((ext_vector_type(4))) float    f32x4;

static __device__ __forceinline__ f32x4 mfma16(f16x8 a, f16x8 b, f32x4 c) {
    return __builtin_amdgcn_mfma_f32_16x16x32_f16(a, b, c, 0, 0, 0);
}

static __device__ __forceinline__ void dma16(void* lds, const void* g) {
    __builtin_amdgcn_global_load_lds(
        (const __attribute__((address_space(1))) unsigned int*)g,
        (__attribute__((address_space(3))) unsigned int*)lds, 16, 0, 0);
}

// best2' = median(best, best2, pk)  given invariant best <= best2.
static __device__ __forceinline__ unsigned med3u(unsigned a, unsigned b, unsigned c) {
    unsigned d;
    asm("v_med3_u32 %0, %1, %2, %3" : "=v"(d) : "v"(a), "v"(b), "v"(c));
    return d;
}

// ws layout (bytes):
//   [0] f32 loss acc   [4] u32 worklist count
//   [256..4352)       eeb[k] = 2048*||e_k||^2 + 2^20  (1024 f32)
//   [8192..139264)    cbH swizzled fp16-hi codebook (row r granule g at r*64 + 8*(g^(r&7)))
//   [139264..270336)  cbL fp16-lo, same swizzle
//   [270336..)        worklist (u32)
#define WS_EEB_F   64
#define WS_CBH_B   8192
#define WS_CBL_B   139264
#define WS_WL_U    67584

__global__ __launch_bounds__(256) void vq_prep(
    const float* __restrict__ emb, float* __restrict__ wsf,
    unsigned* __restrict__ wsu, f16* __restrict__ cbH, f16* __restrict__ cbL,
    float* __restrict__ eeb_g)
{
    const int t   = threadIdx.x;
    const int gid = blockIdx.x * 256 + t;        // 0..8191 granules
    const int row = gid >> 3, gi = gid & 7;
    if (gid == 0) { wsf[0] = 0.f; wsu[1] = 0u; }
    const float* src = emb + (size_t)row * CCH + gi * 8;
    float4 v0 = *(const float4*)(src);
    float4 v1 = *(const float4*)(src + 4);
    float vv[8] = {v0.x, v0.y, v0.z, v0.w, v1.x, v1.y, v1.z, v1.w};
    f16x8 h, l;
    float s = 0.f;
#pragma unroll
    for (int j = 0; j < 8; ++j) {
        f16 hh = (f16)vv[j];
        h[j] = hh;
        l[j] = (f16)(vv[j] - (float)hh);
        s = fmaf(vv[j], vv[j], s);
    }
    const int off = row * 64 + 8 * (gi ^ (row & 7));
    *(f16x8*)(cbH + off) = h;
    *(f16x8*)(cbL + off) = l;
    // ||e||^2: reduce across the 8 granule-threads of this row (adjacent lanes)
    s += __shfl_xor(s, 1, 64);
    s += __shfl_xor(s, 2, 64);
    s += __shfl_xor(s, 4, 64);
    if (gi == 0) eeb_g[row] = fmaf(s, 2048.0f, 1048576.0f);
}

// 8 waves x 32 pixels. LDS ~68KB -> exactly 2 blocks/CU (codebook stays L2-resident).
__global__ __launch_bounds__(512, 4) void vq_main(
    const float* __restrict__ x,
    const float* __restrict__ emb,
    const f16* __restrict__ cbH, const f16* __restrict__ cbL,
    const float* __restrict__ eeb_g,
    float* __restrict__ o, float* __restrict__ idx_out,
    float* __restrict__ acc, unsigned* __restrict__ wl_count,
    unsigned* __restrict__ wl, unsigned cap)
{
    __shared__ __align__(16) char smem[65536];      // 2 x (16K H | 16K L)
    __shared__ float eebl[2][CK];
    __shared__ unsigned bu1[MB], bu2[MB];
    __shared__ float wred[8];

    const int t    = threadIdx.x;
    const int lane = t & 63;
    const int w    = t >> 6;               // 0..7
    const int col  = lane & 15;
    const int quad = lane >> 4;
    const int c7   = col & 7;
    const int sw0  = 8 * (quad ^ c7);      // swizzled granule offset, chans 0..31
    const int sw1  = sw0 ^ 32;             // chans 32..63
    const int n0   = blockIdx.x * MB;
    const int b    = n0 >> 12;
    const int p0   = n0 & 4095;
    const float* xb = x + (size_t)b * (CCH * HW) + p0;

    // wave w stages its 2KB slice of each 16KB H/L region
    auto stage = [&](int chunk, int bufi) {
        const int k0 = chunk * CK;
        char* lb = smem + bufi * 32768;
        const char* gH = (const char*)cbH + (size_t)k0 * 128 + w * 2048 + lane * 16;
        const char* gL = (const char*)cbL + (size_t)k0 * 128 + w * 2048 + lane * 16;
        char* lH = lb + w * 2048;
        char* lL = lb + 16384 + w * 2048;
        dma16(lH,        gH);
        dma16(lH + 1024, gH + 1024);
        dma16(lL,        gL);
        dma16(lL + 1024, gL + 1024);
        if (t < CK) eebl[bufi][t] = eeb_g[k0 + t];
    };

    stage(0, 0);    // DMA in flight while we build A fragments

    // ---- A fragments straight from global (MFMA A-layout, no LDS trip) ----
    // lane holds pixel (w*32 + rt*16 + col), chans kc*32 + quad*8 + j
    f16x8 aH[2][2], aL[2][2];
#pragma unroll
    for (int rt = 0; rt < 2; ++rt) {
        const int pp = w * 32 + rt * 16 + col;
#pragma unroll
        for (int kc = 0; kc < 2; ++kc) {
            f16x8 h, l;
#pragma unroll
            for (int j = 0; j < 8; ++j) {
                const int c = kc * 32 + quad * 8 + j;
                float zs = -2.0f * xb[(size_t)c * HW + pp];
                f16 hh = (f16)zs;
                h[j] = hh;
                l[j] = (f16)(zs - (float)hh);
            }
            aH[rt][kc] = h;
            aL[rt][kc] = l;
        }
    }

    unsigned best[8], best2[8];
#pragma unroll
    for (int s = 0; s < 8; ++s) { best[s] = 0xFFFFFFFFu; best2[s] = 0xFFFFFFFFu; }

    const f32x4 zero4 = {0.f, 0.f, 0.f, 0.f};   // persistent C-init quad

    for (int chunk = 0; chunk < KCODES / CK; ++chunk) {
        const int cur = chunk & 1;
        __syncthreads();                        // chunk's DMA visible to all
        if (chunk + 1 < KCODES / CK) stage(chunk + 1, cur ^ 1);

        const f16* bufH = (const f16*)(smem + cur * 32768);
        const f16* bufL = bufH + 8192;          // +16384 bytes
        const int k0 = chunk * CK;

#pragma unroll
        for (int tile = 0; tile < CK / 16; ++tile) {
            const f16* bh = bufH + (tile * 16 + col) * 64;
            const f16* bl = bufL + (tile * 16 + col) * 64;
            f16x8 bH0 = *(const f16x8*)(bh + sw0);
            f16x8 bH1 = *(const f16x8*)(bh + sw1);
            f16x8 bL0 = *(const f16x8*)(bl + sw0);
            f16x8 bL1 = *(const f16x8*)(bl + sw1);
            const float eebc = eebl[cur][tile * 16 + col];
            const unsigned kb = (unsigned)(k0 + tile * 16 + col);
#pragma unroll
            for (int rt = 0; rt < 2; ++rt) {
                // two independent 3-deep MFMA chains (half the critical path)
                f32x4 u = mfma16(aH[rt][0], bH0, zero4);
                f32x4 v = mfma16(aH[rt][1], bH1, zero4);
                u = mfma16(aL[rt][0], bH0, u);
                v = mfma16(aL[rt][1], bH1, v);
                u = mfma16(aH[rt][0], bL0, u);
                v = mfma16(aH[rt][1], bL1, v);
#pragma unroll
                for (int r = 0; r < 4; ++r) {
                    float uf = fmaf(u[r] + v[r], 2048.0f, eebc);   // in (0, 2^22)
                    unsigned pk = (((unsigned)uf) << 10) | kb;
                    const int s = rt * 4 + r;
                    const unsigned b0 = best[s];
                    best2[s] = med3u(b0, best2[s], pk);      // single VOP3 2nd-best insert
                    best[s]  = min(b0, pk);
                }
            }
        }
    }

    // ---- cross-lane argmin reduce over the 16 code-columns ----
#pragma unroll
    for (int d = 1; d < 16; d <<= 1) {
#pragma unroll
        for (int s = 0; s < 8; ++s) {
            unsigned ob  = __shfl_xor(best[s],  d, 64);
            unsigned ob2 = __shfl_xor(best2[s], d, 64);
            best2[s] = min(min(best2[s], ob2), max(best[s], ob));
            best[s]  = min(best[s], ob);
        }
    }
    if (col == 0) {
#pragma unroll
        for (int rt = 0; rt < 2; ++rt)
#pragma unroll
            for (int r = 0; r < 4; ++r) {
                const int pl = w * 32 + rt * 16 + quad * 4 + r;   // C/D row map
                bu1[pl] = best[rt * 4 + r];
                bu2[pl] = best2[rt * 4 + r];
            }
    }
    __syncthreads();

    // ---- epilogue: 512 threads over 256 pixels x 64 chans (half each) ----
    const int pix  = t & 255;
    const int half = t >> 8;               // 0: chans 0..31, 1: chans 32..63
    const unsigned bu = bu1[pix];
    const unsigned bidx = bu & 1023u;
    if (half == 0) {
        idx_out[n0 + pix] = (float)bidx;
        const unsigned qg = (bu2[pix] >> 10) - (bu >> 10);
        if (qg < MARGIN_Q) {
            unsigned pos = atomicAdd(wl_count, 1u);
            if (pos < cap) wl[pos] = (unsigned)(n0 + pix);
        }
    }
    float ss = 0.f;
    {
        const float4* er4 = (const float4*)(emb + (size_t)bidx * CCH) + half * 8;
        const float* xbt = xb + pix;
        float* ob = o + (size_t)b * (CCH * HW) + p0 + pix;
#pragma unroll
        for (int i = 0; i < 8; ++i) {
            float4 ev = er4[i];
            float evv[4] = {ev.x, ev.y, ev.z, ev.w};
#pragma unroll
            for (int q = 0; q < 4; ++q) {
                const int c = half * 32 + i * 4 + q;
                float xv = xbt[(size_t)c * HW];
                float e  = evv[q];
                ob[(size_t)c * HW] = xv + (e - xv);
                float d = xv - e;
                ss = fmaf(d, d, ss);
            }
        }
    }
    for (int off = 32; off; off >>= 1) ss += __shfl_down(ss, off, 64);
    if (lane == 0) wred[w] = ss;
    __syncthreads();
    if (t == 0) {
        float s2 = 0.f;
#pragma unroll
        for (int q = 0; q < 8; ++q) s2 += wred[q];
        atomicAdd(acc, s2);
    }
}

// Exact fp64 refine: one BLOCK per ambiguous pixel, 4 codes per thread.
__global__ __launch_bounds__(256) void vq_refine(
    const float* __restrict__ x, const float* __restrict__ emb,
    float* __restrict__ o, float* __restrict__ idx_out,
    float* __restrict__ acc, const unsigned* __restrict__ wl_count,
    const unsigned* __restrict__ wl, unsigned cap)
{
    __shared__ float zsh[CCH];
    __shared__ double rbd[4];
    __shared__ int rbi[4];
    __shared__ int s_pk;
    unsigned cnt = *wl_count; if (cnt > cap) cnt = cap;
    const int t = threadIdx.x;

    for (unsigned i = blockIdx.x; i < cnt; i += gridDim.x) {
        const int n = (int)wl[i];
        const int b = n >> 12, p = n & 4095;
        if (t < CCH) zsh[t] = x[(size_t)b * (CCH * HW) + (size_t)t * HW + p];
        __syncthreads();

        double bd = 1e300; int bi = KCODES;
        for (int j = 0; j < 4; ++j) {
            const int k = t + j * 256;
            const float* er = emb + (size_t)k * CCH;
            double d = 0.0;
#pragma unroll
            for (int c = 0; c < CCH; ++c) {
                double tt = (double)zsh[c] - (double)er[c];
                d = fma(tt, tt, d);
            }
            if (d < bd) { bd = d; bi = k; }
        }
        for (int dlt = 1; dlt < 64; dlt <<= 1) {
            double od = __shfl_xor(bd, dlt, 64);
            int    oi = __shfl_xor(bi, dlt, 64);
            if (od < bd || (od == bd && oi < bi)) { bd = od; bi = oi; }
        }
        const int wv = t >> 6;
        if ((t & 63) == 0) { rbd[wv] = bd; rbi[wv] = bi; }
        __syncthreads();
        if (t == 0) {
            double fb = rbd[0]; int fi = rbi[0];
            for (int q = 1; q < 4; ++q)
                if (rbd[q] < fb || (rbd[q] == fb && rbi[q] < fi)) { fb = rbd[q]; fi = rbi[q]; }
            const int old = (int)idx_out[n];
            if (fi != old) { idx_out[n] = (float)fi; s_pk = (old << 16) | fi; }
            else s_pk = -1;
        }
        __syncthreads();
        const int pk = s_pk;
        if (pk >= 0 && t < CCH) {
            const int old = pk >> 16, fi = pk & 0xFFFF;
            const float xv = zsh[t];
            const float eo = emb[(size_t)old * CCH + t];
            const float en = emb[(size_t)fi  * CCH + t];
            o[(size_t)b * (CCH * HW) + (size_t)t * HW + p] = xv + (en - xv);
            const float dn = xv - en, dd = xv - eo;
            float delta = dn * dn - dd * dd;
            for (int off = 32; off; off >>= 1) delta += __shfl_down(delta, off, 64);
            if (t == 0) atomicAdd(acc, delta);
        }
        __syncthreads();
    }
}

__global__ void vq_fin(const float* __restrict__ acc, float* __restrict__ loss) {
    *loss = 1.25f * (*acc) * (1.0f / (float)NELEM);
}

extern "C" void kernel_launch(void* const* d_in, const int* in_sizes, int n_in,
                              void* d_out, int out_size, void* d_ws, size_t ws_size,
                              hipStream_t stream) {
    const float* x   = (const float*)d_in[0];
    const float* emb = (const float*)d_in[1];
    float*    out = (float*)d_out;
    float*    wsf = (float*)d_ws;
    unsigned* wsu = (unsigned*)d_ws;
    char*     wsb = (char*)d_ws;

    float* o_out    = out;
    float* loss_out = out + NELEM;
    float* idx_out  = out + NELEM + 1;
    float* eeb_g    = wsf + WS_EEB_F;
    f16*   cbH      = (f16*)(wsb + WS_CBH_B);
    f16*   cbL      = (f16*)(wsb + WS_CBL_B);
    unsigned* wl    = wsu + WS_WL_U;
    unsigned cap = 0;
    if (ws_size / 4 > WS_WL_U) {
        size_t c = ws_size / 4 - WS_WL_U;
        cap = (unsigned)(c > NPIX ? NPIX : c);
    }

    vq_prep<<<32, 256, 0, stream>>>(emb, wsf, wsu, cbH, cbL, eeb_g);
    vq_main<<<NPIX / MB, 512, 0, stream>>>(x, emb, cbH, cbL, eeb_g, o_out,
                                           idx_out, wsf, wsu + 1, wl, cap);
    vq_refine<<<512, 256, 0, stream>>>(x, emb, o_out, idx_out, wsf,
                                       wsu + 1, wl, cap);
    vq_fin<<<1, 1, 0, stream>>>(wsf, loss_out);
}